// Round 8
// baseline (456.924 us; speedup 1.0000x reference)
//
#include <hip/hip_runtime.h>
#include <cstdint>
#include <cstddef>

#define NOBJ 32
#define NP   992
#define DD   256
#define SP   196   // 14*14
#define OC   151
#define RC   51
#define RED  64
#define KIN  4251  // 4096 + 151 + 4
#define CH   128   // emb1 k-chunks
#define KPC  34    // ceil(4251/128)

// ---- ws layout (float offsets) ----
#define OFF_PART   0u         // 128*32*256 = 1048576
#define OFF_OBJF   1048576u   // 8192
#define OFF_SALL   1056768u   // 992*768 = 761856
#define OFF_RELF   1818624u   // 253952
#define OFF_H      2072576u   // 262144
#define OFF_WOPT   2826240u   // 38656
#define OFF_WRPT   2864896u   // 13056

#define TR_TOT 51712   // WopT (38656) + WrpT (13056) only

#define TCH  32        // channels per union tile
#define NTIL 8         // 256 / TCH
#define TFLT 6272      // floats per tile (TCH*SP)
#define BUFSZ 6304     // + 28-float slack (slice-7 tail overrun), 16B-mult

// async global->LDS (gfx950): no VGPR round-trip, dest = wave base + lane*16
#if defined(__has_builtin)
#if __has_builtin(__builtin_amdgcn_global_load_lds)
#define HAS_GLLDS 1
#endif
#endif

__device__ __forceinline__ void gl_lds16(const float* g, float* l) {
#ifdef HAS_GLLDS
  __builtin_amdgcn_global_load_lds(
      (const __attribute__((address_space(1))) void*)g,
      (__attribute__((address_space(3))) void*)l,
      16, 0, 0);
#else
  *(float4*)l = *(const float4*)g;   // synchronous fallback
#endif
}

// ============ K_PRE: union(0..991) + emb1(992..1119) + transpose(1120..1183)
// Union: double-buffered LDS via global_load_lds (zero staging VGPRs -> the
// round-2/3 spill hazard is structurally impossible), ONE barrier per tile.
// 53KB LDS -> 3 blocks/CU (12 waves). Prefetch ti+1 lands during compute(ti).
__global__ void __launch_bounds__(256, 3)
k_pre(const float* __restrict__ uf,
      const float* __restrict__ bbox,
      const int* __restrict__ pairs,
      const float* __restrict__ roi,
      const float* __restrict__ logits,
      const float* __restrict__ W1,
      const float* __restrict__ Wop, const float* __restrict__ Wrp,
      float* __restrict__ sAll, float* __restrict__ part,
      float* __restrict__ WopT, float* __restrict__ WrpT) {
  const int b = blockIdx.x, t = threadIdx.x;
  if (b < NP) {
    const int p = b;
    __shared__ __align__(16) float buf[2][BUFSZ];   // 2 x 25216 B
    __shared__ __align__(16) float mS[224];         // masks padded to 224
    __shared__ __align__(16) float mO[224];
    __shared__ __align__(16) float mB[224];
    if (t < 224) {
      float sm = 0.f, om = 0.f, bm = 0.f;
      if (t < SP) {
        int si = pairs[2 * p], oi = pairs[2 * p + 1];
        float sx1 = bbox[si * 4 + 0], sy1 = bbox[si * 4 + 1];
        float sx2 = bbox[si * 4 + 2], sy2 = bbox[si * 4 + 3];
        float ox1 = bbox[oi * 4 + 0], oy1 = bbox[oi * 4 + 1];
        float ox2 = bbox[oi * 4 + 2], oy2 = bbox[oi * 4 + 3];
        float ux = fminf(sx1, ox1), uy = fminf(sy1, oy1);
        float xr = 14.f / fmaxf(sx2 - ux, ox2 - ux);
        float yr = 14.f / fmaxf(sy2 - uy, oy2 - uy);
        float xs0 = rintf((sx1 - ux) * xr), xs1 = rintf((sx2 - ux) * xr);
        float xo0 = rintf((ox1 - ux) * xr), xo1 = rintf((ox2 - ux) * xr);
        float ys0 = rintf((sy1 - uy) * yr), ys1 = rintf((sy2 - uy) * yr);
        float yo0 = rintf((oy1 - uy) * yr), yo1 = rintf((oy2 - uy) * yr);
        int a = t / 14, bb = t - a * 14;
        float fa = (float)a, fb = (float)bb;
        sm = (fa >= xs0 && fa < xs1 && fb >= ys0 && fb < ys1) ? 1.f : 0.f;
        om = (fa >= xo0 && fa < xo1 && fb >= yo0 && fb < yo1) ? 1.f : 0.f;
        bm = fminf(fmaxf(1.f - sm - om, 0.f), 1.f);
      }
      mS[t] = sm; mO[t] = om; mB[t] = bm;
    }
    if (t < 28) { buf[0][TFLT + t] = 0.f; buf[1][TFLT + t] = 0.f; }
    const float* gbase = uf + (size_t)p * (DD * SP);
#define ISSUE_TILE(TI, BI)                                                    \
    { const float* src = gbase + (TI) * TFLT + t * 4;                         \
      float* dst = &buf[BI][t * 4];                                           \
      gl_lds16(src, dst);                 gl_lds16(src + 1024, dst + 1024);   \
      gl_lds16(src + 2048, dst + 2048);   gl_lds16(src + 3072, dst + 3072);   \
      gl_lds16(src + 4096, dst + 4096);   gl_lds16(src + 5120, dst + 5120);   \
      if (t < 32) gl_lds16(src + 6144, dst + 6144); }
    ISSUE_TILE(0, 0)
    __syncthreads();                        // masks + tile0 landed (vmcnt drain)
    const int cl = t >> 3, o = t & 7;       // channel-in-tile, 28-float slice
    const int roff = cl * SP + o * 28;      // 16B-aligned
    const float* msp = mS + o * 28;
    const float* mop = mO + o * 28;
    const float* mbp = mB + o * 28;
    const float inv = 1.f / 196.f;
#pragma unroll 1
    for (int ti = 0; ti < NTIL; ++ti) {
      if (ti + 1 < NTIL) ISSUE_TILE(ti + 1, (ti + 1) & 1)   // async into other buf
      const float* row = &buf[ti & 1][roff];
      float aS = 0.f, aO = 0.f, aB = 0.f;
#pragma unroll
      for (int j = 0; j < 7; ++j) {
        float4 v = *(const float4*)&row[4 * j];
        float4 x = *(const float4*)&msp[4 * j];
        float4 y = *(const float4*)&mop[4 * j];
        float4 z = *(const float4*)&mbp[4 * j];
        aS += v.x * x.x + v.y * x.y + v.z * x.z + v.w * x.w;
        aO += v.x * y.x + v.y * y.y + v.z * y.z + v.w * y.w;
        aB += v.x * z.x + v.y * z.y + v.z * z.z + v.w * z.w;
      }
      aS += __shfl_xor(aS, 1); aS += __shfl_xor(aS, 2); aS += __shfl_xor(aS, 4);
      aO += __shfl_xor(aO, 1); aO += __shfl_xor(aO, 2); aO += __shfl_xor(aO, 4);
      aB += __shfl_xor(aB, 1); aB += __shfl_xor(aB, 2); aB += __shfl_xor(aB, 4);
      const int ch = ti * TCH + cl;
      if (o == 0)      sAll[(size_t)p * 768 + ch]       = aS * inv;
      else if (o == 1) sAll[(size_t)p * 768 + 256 + ch] = aO * inv;
      else if (o == 2) sAll[(size_t)p * 768 + 512 + ch] = aB * inv;
      __syncthreads();   // drains prefetch (landed under compute) + read fence
    }
#undef ISSUE_TILE
  } else if (b < NP + CH) {
    // ---- emb1 split-K partial ----
    const int chunk = b - NP;
    int k0 = chunk * KPC;
    int k1 = k0 + KPC; if (k1 > KIN) k1 = KIN;
    float acc[NOBJ];
#pragma unroll
    for (int i = 0; i < NOBJ; ++i) acc[i] = 0.f;
#pragma unroll 2
    for (int k = k0; k < k1; ++k) {
      float w = W1[(size_t)k * DD + t];
      const float* xp; int stride;
      if (k < 4096)            { xp = roi    + k;               stride = 4096; }
      else if (k < 4096 + OC)  { xp = logits + (k - 4096);      stride = OC;   }
      else                     { xp = bbox   + (k - 4096 - OC); stride = 4;    }
#pragma unroll
      for (int i = 0; i < NOBJ; ++i) { acc[i] += xp[0] * w; xp += stride; }
    }
    float* pout = part + (size_t)chunk * (NOBJ * DD) + t;
#pragma unroll
    for (int i = 0; i < NOBJ; ++i) pout[i * DD] = acc[i];
  } else {
    // ---- head-weight transposes only (WopT, WrpT) ----
    for (int o = (b - NP - CH) * 256 + t; o < TR_TOT; o += 64 * 256) {
      float v; float* dst;
      if (o < 38656) { int q = o;         v = Wop[(q & 255) * OC + (q >> 8)]; dst = WopT + q; }
      else           { int q = o - 38656; v = Wrp[(q & 255) * RC + (q >> 8)]; dst = WrpT + q; }
      *dst = v;
    }
  }
}

// 8-step dot: 8 coalesced weight loads (stride STR floats) x 2 pairs of
// float4 activation broadcasts from LDS. 8 independent loads in flight.
#define DOT8(WP, STR, X0, X1, K, A0, A1)                                      \
  { float w0v = (WP)[(size_t)((K) + 0) * (STR)],                              \
          w1v = (WP)[(size_t)((K) + 1) * (STR)],                              \
          w2v = (WP)[(size_t)((K) + 2) * (STR)],                              \
          w3v = (WP)[(size_t)((K) + 3) * (STR)],                              \
          w4v = (WP)[(size_t)((K) + 4) * (STR)],                              \
          w5v = (WP)[(size_t)((K) + 5) * (STR)],                              \
          w6v = (WP)[(size_t)((K) + 6) * (STR)],                              \
          w7v = (WP)[(size_t)((K) + 7) * (STR)];                              \
    float4 xa0 = *(const float4*)&(X0)[(K)];                                  \
    float4 xb0 = *(const float4*)&(X0)[(K) + 4];                              \
    float4 xa1 = *(const float4*)&(X1)[(K)];                                  \
    float4 xb1 = *(const float4*)&(X1)[(K) + 4];                              \
    A0 += xa0.x * w0v + xa0.y * w1v + xa0.z * w2v + xa0.w * w3v               \
        + xb0.x * w4v + xb0.y * w5v + xb0.z * w6v + xb0.w * w7v;              \
    A1 += xa1.x * w0v + xa1.y * w1v + xa1.z * w2v + xa1.w * w3v               \
        + xb1.x * w4v + xb1.y * w5v + xb1.z * w6v + xb1.w * w7v; }

// ============ K_MID2: rel = 2 pairs/block, thread owns 1 output column =====
__global__ void __launch_bounds__(256, 4)
k_mid2(const float* __restrict__ sAll,
       const float* __restrict__ f1w, const float* __restrict__ f1b,
       const float* __restrict__ f2w, const float* __restrict__ f2b,
       const float* __restrict__ Wc1, const float* __restrict__ bc1,
       const float* __restrict__ Wc2, const float* __restrict__ bc2,
       const float* __restrict__ Wg,
       const float* __restrict__ part, const float* __restrict__ b1,
       const float* __restrict__ W2,  const float* __restrict__ b2,
       float* __restrict__ relf, float* __restrict__ objf,
       float* __restrict__ H) {
  const int b = blockIdx.x, t = threadIdx.x;
  __shared__ __align__(16) float sg[2][768];
  __shared__ __align__(16) float ha[2][192];
  __shared__ __align__(16) float h2[2][256];
  __shared__ __align__(16) float rf[2][256];
  __shared__ __align__(16) float hob[256];
  __shared__ __align__(16) float eob[256];
  if (b < NP / 2) {
    const int r0 = b * 2;
    const int tt = t;
    for (int j = t; j < 384; j += 256) {
      int pr = j / 192, off = j - pr * 192;
      ((float4*)&sg[pr][0])[off] =
          ((const float4*)(sAll + (size_t)(r0 + pr) * 768))[off];
    }
    __syncthreads();
    // ---- P1: att fc1 (out 192, K=256 per branch) ----
    if (tt < 192) {
      const int br = tt >> 6;
      const float* wp = f1w + br * 16384 + (tt & 63);   // f1w[br][k][rc]
      const float* x0 = &sg[0][br * 256];
      const float* x1 = &sg[1][br * 256];
      float a0 = 0.f, a1 = 0.f;
      for (int k8 = 0; k8 < 32; ++k8) DOT8(wp, 64, x0, x1, k8 * 8, a0, a1)
      float bb = f1b[tt];
      ha[0][tt] = fmaxf(a0 + bb, 0.f);
      ha[1][tt] = fmaxf(a1 + bb, 0.f);
    }
    __syncthreads();
    // ---- P2: att fc2 + sigmoid gate (out 768, K=64 per branch) ----
#pragma unroll
    for (int br = 0; br < 3; ++br) {
      const float* wp = f2w + br * 16384 + tt;          // f2w[br][red][c]
      const float* x0 = &ha[0][br * 64];
      const float* x1 = &ha[1][br * 64];
      float a0 = 0.f, a1 = 0.f;
      for (int r8 = 0; r8 < 8; ++r8) DOT8(wp, 256, x0, x1, r8 * 8, a0, a1)
      float bb = f2b[br * 256 + tt];
      sg[0][br * 256 + tt] *= 1.f / (1.f + expf(-(a0 + bb)));
      sg[1][br * 256 + tt] *= 1.f / (1.f + expf(-(a1 + bb)));
    }
    __syncthreads();
    // ---- P3: rel fc1 768->256 relu ----
    {
      const float* wp = Wc1 + tt;
      const float* x0 = &sg[0][0];
      const float* x1 = &sg[1][0];
      float a0 = 0.f, a1 = 0.f;
      for (int k8 = 0; k8 < 96; ++k8) DOT8(wp, 256, x0, x1, k8 * 8, a0, a1)
      float bb = bc1[tt];
      h2[0][tt] = fmaxf(a0 + bb, 0.f);
      h2[1][tt] = fmaxf(a1 + bb, 0.f);
    }
    __syncthreads();
    // ---- P4: rel fc2 -> relf + stash ----
    {
      const float* wp = Wc2 + tt;
      const float* x0 = &h2[0][0];
      const float* x1 = &h2[1][0];
      float a0 = 0.f, a1 = 0.f;
      for (int k8 = 0; k8 < 32; ++k8) DOT8(wp, 256, x0, x1, k8 * 8, a0, a1)
      float bb = bc2[tt];
      float v0 = a0 + bb, v1 = a1 + bb;
      relf[(size_t)r0 * DD + tt] = v0;
      relf[(size_t)(r0 + 1) * DD + tt] = v1;
      rf[0][tt] = v0; rf[1][tt] = v1;
    }
    __syncthreads();
    // ---- P5: H_rel = relf @ Wg ----
    {
      const float* wp = Wg + tt;
      const float* x0 = &rf[0][0];
      const float* x1 = &rf[1][0];
      float a0 = 0.f, a1 = 0.f;
      for (int k8 = 0; k8 < 32; ++k8) DOT8(wp, 256, x0, x1, k8 * 8, a0, a1)
      H[(size_t)(NOBJ + r0) * DD + tt] = a0;
      H[(size_t)(NOBJ + r0 + 1) * DD + tt] = a1;
    }
  } else {
    // ---- emb2 + H_obj: 1 object per block, coalesced original W2/Wg ----
    const int i = b - NP / 2;   // 0..31
    float s[8];
#pragma unroll
    for (int u = 0; u < 8; ++u) s[u] = 0.f;
#pragma unroll
    for (int c0 = 0; c0 < CH; c0 += 8) {
#pragma unroll
      for (int u = 0; u < 8; ++u)
        s[u] += part[(size_t)(c0 + u) * (NOBJ * DD) + i * DD + t];
    }
    float tot = ((s[0] + s[1]) + (s[2] + s[3])) + ((s[4] + s[5]) + (s[6] + s[7]));
    hob[t] = fmaxf(tot + b1[t], 0.f);
    __syncthreads();
    {
      float a = 0.f;
#pragma unroll 4
      for (int k4 = 0; k4 < 64; ++k4) {
        float4 hv = *((const float4*)hob + k4);
        int k = 4 * k4;
        a += hv.x * W2[k * 256 + t]       + hv.y * W2[(k + 1) * 256 + t]
           + hv.z * W2[(k + 2) * 256 + t] + hv.w * W2[(k + 3) * 256 + t];
      }
      float v = a + b2[t];
      objf[i * DD + t] = v;
      eob[t] = v;
    }
    __syncthreads();
    {
      float a = 0.f;
#pragma unroll 4
      for (int k4 = 0; k4 < 64; ++k4) {
        float4 ev = *((const float4*)eob + k4);
        int k = 4 * k4;
        a += ev.x * Wg[k * 256 + t]       + ev.y * Wg[(k + 1) * 256 + t]
           + ev.z * Wg[(k + 2) * 256 + t] + ev.w * Wg[(k + 3) * 256 + t];
      }
      H[(size_t)i * DD + t] = a;
    }
  }
}

// ============ K_HEADS: rel(0..247, 4 pairs) + obj(248..279), 1024 thr ======
__global__ void __launch_bounds__(1024, 1)
k_heads(const float* __restrict__ H, const float* __restrict__ objf,
        const float* __restrict__ relf, const int* __restrict__ pairs,
        const float* __restrict__ bg,
        const float* __restrict__ WopT, const float* __restrict__ bop,
        const float* __restrict__ WrpT, const float* __restrict__ brp,
        float* __restrict__ out) {
  const int b = blockIdx.x, t = threadIdx.x;
  const int p = t >> 8, tt = t & 255;
  if (b < NP / 4) {
    __shared__ __align__(16) float gr[4][DD];
    __shared__ float red[4][4][64];
    const int r = b * 4 + p;
    int si = pairs[2 * r], oi = pairs[2 * r + 1];
    float hsum = H[si * DD + tt] + H[oi * DD + tt] + H[(size_t)(NOBJ + r) * DD + tt];
    gr[p][tt] = fmaxf(hsum * (1.f / 3.f) + bg[tt], 0.f) + relf[(size_t)r * DD + tt];
    __syncthreads();
    const int q = tt >> 6, c = tt & 63;
    float a = 0.f;
    if (c < RC) {
      const float4* w4 = (const float4*)(WrpT + c * 256 + q * 64);
#pragma unroll
      for (int j = 0; j < 16; ++j) {
        float4 wv = w4[j];
        float4 gv = *(const float4*)&gr[p][q * 64 + 4 * j];
        a += gv.x * wv.x + gv.y * wv.y + gv.z * wv.z + gv.w * wv.w;
      }
    }
    red[p][q][c] = a;
    __syncthreads();
    if (tt < RC)
      out[NOBJ * OC + (size_t)r * RC + tt] =
          red[p][0][tt] + red[p][1][tt] + red[p][2][tt] + red[p][3][tt] + brp[tt];
  } else {
    const int i = b - NP / 4;   // 0..31
    const int slice = p;
    __shared__ int2 pr[NP];
    __shared__ float red2[4][DD];
    __shared__ __align__(16) float gro[DD];
    const int2* p2 = (const int2*)pairs;
    for (int r = t; r < NP; r += 1024) pr[r] = p2[r];
    __syncthreads();
    float acc = 0.f;
    if (slice == 0) {
#pragma unroll 8
      for (int j = 0; j < NOBJ; ++j) acc += H[j * DD + tt];
    }
    const int rbeg = slice * 248;
#pragma unroll 8
    for (int r = rbeg; r < rbeg + 248; ++r) {
      int2 q = pr[r];
      float v = H[(size_t)(NOBJ + r) * DD + tt];
      if (q.x == i || q.y == i) acc += v;
    }
    red2[slice][tt] = acc;
    __syncthreads();
    if (t < DD) {
      float pre = (red2[0][t] + red2[1][t] + red2[2][t] + red2[3][t]) * (1.f / 94.f);
      gro[t] = fmaxf(pre + bg[t], 0.f) + objf[i * DD + t];
    }
    __syncthreads();
    float hsum = 0.f;
    if (tt < OC) {
      const float4* w4 = (const float4*)(WopT + tt * 256 + slice * 64);
#pragma unroll
      for (int j = 0; j < 16; ++j) {
        float4 wv = w4[j];
        float4 gv = *(const float4*)&gro[slice * 64 + 4 * j];
        hsum += gv.x * wv.x + gv.y * wv.y + gv.z * wv.z + gv.w * wv.w;
      }
    }
    red2[slice][tt] = hsum;
    __syncthreads();
    if (t < OC)
      out[i * OC + t] = red2[0][t] + red2[1][t] + red2[2][t] + red2[3][t] + bop[t];
  }
}

extern "C" void kernel_launch(void* const* d_in, const int* in_sizes, int n_in,
                              void* d_out, int out_size, void* d_ws, size_t ws_size,
                              hipStream_t stream) {
  const float* roi   = (const float*)d_in[0];
  const float* bbox  = (const float*)d_in[1];
  const float* logit = (const float*)d_in[2];
  const float* uf    = (const float*)d_in[3];
  const int*   pairs = (const int*)d_in[4];
  const float* W1    = (const float*)d_in[5];
  const float* b1    = (const float*)d_in[6];
  const float* W2    = (const float*)d_in[7];
  const float* b2    = (const float*)d_in[8];
  const float* fc1w  = (const float*)d_in[9];
  const float* fc1b  = (const float*)d_in[10];
  const float* fc2w  = (const float*)d_in[11];
  const float* fc2b  = (const float*)d_in[12];
  const float* Wc1   = (const float*)d_in[13];
  const float* bc1   = (const float*)d_in[14];
  const float* Wc2   = (const float*)d_in[15];
  const float* bc2   = (const float*)d_in[16];
  const float* Wg    = (const float*)d_in[17];
  const float* bg    = (const float*)d_in[18];
  const float* Wop   = (const float*)d_in[19];
  const float* bop   = (const float*)d_in[20];
  const float* Wrp   = (const float*)d_in[21];
  const float* brp   = (const float*)d_in[22];

  float* ws    = (float*)d_ws;
  float* part  = ws + OFF_PART;
  float* objf  = ws + OFF_OBJF;
  float* sAll  = ws + OFF_SALL;
  float* relf  = ws + OFF_RELF;
  float* Hbuf  = ws + OFF_H;
  float* WopT  = ws + OFF_WOPT;
  float* WrpT  = ws + OFF_WRPT;
  float* out   = (float*)d_out;

  k_pre<<<NP + CH + 64, 256, 0, stream>>>(uf, bbox, pairs, roi, logit, W1,
                                          Wop, Wrp, sAll, part, WopT, WrpT);
  k_mid2<<<NP / 2 + NOBJ, 256, 0, stream>>>(sAll, fc1w, fc1b, fc2w, fc2b,
                                            Wc1, bc1, Wc2, bc2, Wg,
                                            part, b1, W2, b2, relf, objf, Hbuf);
  k_heads<<<NP / 4 + NOBJ, 1024, 0, stream>>>(Hbuf, objf, relf, pairs, bg,
                                              WopT, bop, WrpT, brp, out);
}